// Round 6
// baseline (487.292 us; speedup 1.0000x reference)
//
#include <hip/hip_runtime.h>
#include <math.h>

#define HDIM 128
#define BSH 9                 // bucket shift: 512 nodes per bucket
#define CH 4096               // edges per binning chunk
#define NPB 256               // node-blocks per feature slice (gather)

typedef __attribute__((ext_vector_type(8))) short short8;
typedef __attribute__((ext_vector_type(4))) float f32x4;

__device__ inline unsigned short bf16_hi(float f) {
    return (unsigned short)(__float_as_uint(f) >> 16);
}
__device__ inline unsigned short bf16_rn(float f) {
    unsigned int u = __float_as_uint(f);
    return (unsigned short)((u + 0x7FFF + ((u >> 16) & 1)) >> 16);
}
__device__ inline float bf2f(unsigned short h) {
    return __uint_as_float((unsigned int)h << 16);
}

// ---------- 1. bucket histogram (196 buckets, LDS-aggregated) ----------
__global__ __launch_bounds__(256) void binA_kernel(
    const int* __restrict__ dst, int E, int* __restrict__ bcnt) {
    __shared__ int hist[256];
    const int t = threadIdx.x;
    const int c0 = blockIdx.x * CH;
    hist[t] = 0;
    __syncthreads();
    #pragma unroll
    for (int k = 0; k < CH / 256; ++k) {
        int e = c0 + t + (k << 8);
        if (e < E) atomicAdd(&hist[dst[e] >> BSH], 1);
    }
    __syncthreads();
    if (hist[t] > 0) atomicAdd(&bcnt[t], hist[t]);
}

// ---------- 2. scan bucket counts -> bbase / bcur; row_ptr[n]=E ----------
__global__ __launch_bounds__(256) void scanB_kernel(
    const int* __restrict__ bcnt, int* __restrict__ bbase, int* __restrict__ bcur,
    int* __restrict__ row_ptr, int NB, int n, int E) {
    __shared__ int s[256];
    const int t = threadIdx.x;
    int v = (t < NB) ? bcnt[t] : 0;
    s[t] = v;
    __syncthreads();
    for (int off = 1; off < 256; off <<= 1) {
        int u = (t >= off) ? s[t - off] : 0;
        __syncthreads();
        s[t] += u;
        __syncthreads();
    }
    int excl = s[t] - v;
    if (t < NB) { bbase[t] = excl; bcur[t] = excl; }
    if (t == 0) { bbase[NB] = E; row_ptr[n] = E; }
}

// ---------- 3. bin edges into bucket-major eb[] ----------
__global__ __launch_bounds__(256) void binB_kernel(
    const int* __restrict__ ei, int E,
    int* __restrict__ bcur, int2* __restrict__ eb) {
    __shared__ int hist[256], base[256], cur[256];
    const int t = threadIdx.x;
    const int c0 = blockIdx.x * CH;
    hist[t] = 0;
    __syncthreads();

    int sv[CH / 256], dv[CH / 256];
    #pragma unroll
    for (int k = 0; k < CH / 256; ++k) {
        int e = c0 + t + (k << 8);
        if (e < E) {
            sv[k] = ei[e];
            dv[k] = ei[E + e];
            atomicAdd(&hist[dv[k] >> BSH], 1);
        } else {
            dv[k] = -1;
        }
    }
    __syncthreads();
    if (hist[t] > 0) base[t] = atomicAdd(&bcur[t], hist[t]);
    cur[t] = 0;
    __syncthreads();
    #pragma unroll
    for (int k = 0; k < CH / 256; ++k) {
        if (dv[k] >= 0) {
            int bkt = dv[k] >> BSH;
            int o = atomicAdd(&cur[bkt], 1);
            eb[(size_t)base[bkt] + o] = make_int2(sv[k], dv[k]);
        }
    }
}

// ---------- 4. per-bucket: LDS degree hist + scan -> row_ptr/dinv, CSR fill ----------
__global__ __launch_bounds__(512) void binC_kernel(
    const int2* __restrict__ eb, const int* __restrict__ bbase,
    int* __restrict__ row_ptr, float* __restrict__ dinv,
    int* __restrict__ col, int n) {
    __shared__ int hist[512];
    __shared__ int cur[512];
    const int t = threadIdx.x;
    const int b = blockIdx.x;
    const int node0 = b << BSH;
    const int e0 = bbase[b];
    const int e1 = bbase[b + 1];

    hist[t] = 0;
    __syncthreads();
    for (int e = e0 + t; e < e1; e += 512)
        atomicAdd(&hist[eb[e].y - node0], 1);
    __syncthreads();
    int v = hist[t];
    // exclusive scan over 512 (Hillis-Steele, in place)
    for (int off = 1; off < 512; off <<= 1) {
        int u = (t >= off) ? hist[t - off] : 0;
        __syncthreads();
        hist[t] += u;
        __syncthreads();
    }
    int excl = hist[t] - v;
    int node = node0 + t;
    if (node < n) {
        row_ptr[node] = e0 + excl;
        dinv[node] = rsqrtf((float)v + 1.0f);
    }
    cur[t] = e0 + excl;
    __syncthreads();
    for (int e = e0 + t; e < e1; e += 512) {
        int2 p = eb[e];
        int pos = atomicAdd(&cur[p.y - node0], 1);
        col[pos] = p.x;
    }
}

// ---------- 5. MFMA split-bf16 GEMM: gbs[slice][node*16+c] = bf16(dinv*(x@W^T)) ----------
// 3-term split: x*W ~= xh*Wh + xl*Wh + xh*Wl, fp32 accumulate.
// Output slice-major (8 slices of 16 cols, each slice n*16 contiguous) so a
// feature-slice is a 3.2 MB contiguous region (one XCD's L2 in gather).
__global__ __launch_bounds__(256) void mfma_gemm_kernel(
    const float* __restrict__ x, const float* __restrict__ W,
    const float* __restrict__ dinv, unsigned short* __restrict__ gbs, int n) {
    __shared__ uint4 Wh[2048];   // 32 KB
    __shared__ uint4 Wl[2048];   // 32 KB

    const int t = threadIdx.x;
    const int wave = t >> 6;
    const int lane = t & 63;
    const int q = lane >> 4;
    const int m = lane & 15;

    for (int idx = t; idx < 2048; idx += 256) {
        const int j = idx >> 4;
        const int c = idx & 15;
        const float4* wp = (const float4*)(W + (size_t)j * HDIM + c * 8);
        float4 va = wp[0], vb = wp[1];
        float vs[8] = {va.x, va.y, va.z, va.w, vb.x, vb.y, vb.z, vb.w};
        unsigned short h[8], l[8];
        #pragma unroll
        for (int k = 0; k < 8; ++k) {
            h[k] = bf16_hi(vs[k]);
            float hf = __uint_as_float((unsigned int)h[k] << 16);
            l[k] = bf16_hi(vs[k] - hf);
        }
        uint4 hch, lch;
        hch.x = (unsigned int)h[0] | ((unsigned int)h[1] << 16);
        hch.y = (unsigned int)h[2] | ((unsigned int)h[3] << 16);
        hch.z = (unsigned int)h[4] | ((unsigned int)h[5] << 16);
        hch.w = (unsigned int)h[6] | ((unsigned int)h[7] << 16);
        lch.x = (unsigned int)l[0] | ((unsigned int)l[1] << 16);
        lch.y = (unsigned int)l[2] | ((unsigned int)l[3] << 16);
        lch.z = (unsigned int)l[4] | ((unsigned int)l[5] << 16);
        lch.w = (unsigned int)l[6] | ((unsigned int)l[7] << 16);
        const int sidx = (j << 4) | (c ^ (j & 15));
        Wh[sidx] = hch;
        Wl[sidx] = lch;
    }
    __syncthreads();

    const int ngroups = (n + 127) >> 7;
    for (int grp = blockIdx.x; grp < ngroups; grp += gridDim.x) {
        const int rowbase = (grp << 7) + (wave << 5);

        f32x4 acc[2][8];
        #pragma unroll
        for (int mt = 0; mt < 2; ++mt)
            #pragma unroll
            for (int ct = 0; ct < 8; ++ct)
                acc[mt][ct] = (f32x4){0.f, 0.f, 0.f, 0.f};

        #pragma unroll
        for (int kk = 0; kk < 4; ++kk) {
            short8 ah[2], al[2];
            #pragma unroll
            for (int mt = 0; mt < 2; ++mt) {
                const int r = rowbase + (mt << 4) + m;
                float vs[8];
                if (r < n) {
                    const float4* xp = (const float4*)(x + (size_t)r * HDIM + (kk << 5) + (q << 3));
                    float4 va = xp[0], vb = xp[1];
                    vs[0] = va.x; vs[1] = va.y; vs[2] = va.z; vs[3] = va.w;
                    vs[4] = vb.x; vs[5] = vb.y; vs[6] = vb.z; vs[7] = vb.w;
                } else {
                    #pragma unroll
                    for (int k = 0; k < 8; ++k) vs[k] = 0.f;
                }
                #pragma unroll
                for (int k = 0; k < 8; ++k) {
                    unsigned short h = bf16_hi(vs[k]);
                    float hf = __uint_as_float((unsigned int)h << 16);
                    unsigned short lo = bf16_hi(vs[k] - hf);
                    ah[mt][k] = (short)h;
                    al[mt][k] = (short)lo;
                }
            }
            #pragma unroll
            for (int ct = 0; ct < 8; ++ct) {
                const int nn = (ct << 4) + m;
                const int sidx = (nn << 4) | (((kk << 2) + q) ^ m);
                short8 bh = *(const short8*)&Wh[sidx];
                short8 bl = *(const short8*)&Wl[sidx];
                #pragma unroll
                for (int mt = 0; mt < 2; ++mt) {
                    acc[mt][ct] = __builtin_amdgcn_mfma_f32_16x16x32_bf16(ah[mt], bh, acc[mt][ct], 0, 0, 0);
                    acc[mt][ct] = __builtin_amdgcn_mfma_f32_16x16x32_bf16(al[mt], bh, acc[mt][ct], 0, 0, 0);
                    acc[mt][ct] = __builtin_amdgcn_mfma_f32_16x16x32_bf16(ah[mt], bl, acc[mt][ct], 0, 0, 0);
                }
            }
        }

        // ---- scale by dinv, store slice-major bf16 ----
        #pragma unroll
        for (int mt = 0; mt < 2; ++mt) {
            #pragma unroll
            for (int rr = 0; rr < 4; ++rr) {
                const int grow = rowbase + (mt << 4) + (q << 2) + rr;
                if (grow < n) {
                    const float di = dinv[grow];
                    #pragma unroll
                    for (int ct = 0; ct < 8; ++ct)
                        gbs[((size_t)ct * n + grow) * 16 + m] = bf16_rn(acc[mt][ct][rr] * di);
                }
            }
        }
    }
}

// ---------- 6. XCD-sliced pull gather + fused epilogue ----------
// slice = blockIdx & 7 (block->XCD round-robin heuristic): each XCD's random
// reads hit only its 3.2 MB slice (L2-resident). 16 lanes per edge (c=col),
// 4 edges in flight per wave. out = dinv_i*(sum m_src + m_i) + b, PReLU.
__global__ __launch_bounds__(256) void gather_kernel(
    const int* __restrict__ row_ptr, const int* __restrict__ col,
    const unsigned short* __restrict__ gbs, const float* __restrict__ dinv,
    const float* __restrict__ bias, const float* __restrict__ prelu_a,
    float* __restrict__ out, int n) {
    const int slice = blockIdx.x & 7;
    const int bg = blockIdx.x >> 3;
    const int w = threadIdx.x >> 6;
    const int lane = threadIdx.x & 63;
    const int sub = lane >> 4;
    const int c = lane & 15;
    const unsigned short* __restrict__ gs = gbs + (size_t)slice * n * 16;

    const int gwid = bg * 4 + w;           // wave id within slice
    const int WPS = NPB * 4;               // waves per slice
    const int per = (n + WPS - 1) / WPS;
    int i0 = gwid * per;
    int i1 = i0 + per; if (i1 > n) i1 = n;
    if (i0 >= n) return;

    const float aa = prelu_a[0];
    const float bb = bias[slice * 16 + c];
    int beg = row_ptr[i0];
    for (int i = i0; i < i1; ++i) {
        int end = row_ptr[i + 1];
        float acc = 0.f;
        for (int e = beg + sub; e < end; e += 4) {
            int s = col[e];
            acc += bf2f(gs[(size_t)s * 16 + c]);
        }
        acc += __shfl_xor(acc, 16);
        acc += __shfl_xor(acc, 32);
        if (sub == 0) {
            float di = dinv[i];
            float v = di * (acc + bf2f(gs[(size_t)i * 16 + c])) + bb;
            v = v >= 0.f ? v : aa * v;
            out[(size_t)i * HDIM + slice * 16 + c] = v;
        }
        beg = end;
    }
}

extern "C" void kernel_launch(void* const* d_in, const int* in_sizes, int n_in,
                              void* d_out, int out_size, void* d_ws, size_t ws_size,
                              hipStream_t stream) {
    const float* x  = (const float*)d_in[0];
    const int*   ei = (const int*)d_in[1];   // edge_index (2, E), int32
    const float* W  = (const float*)d_in[2];
    const float* b  = (const float*)d_in[3];
    const float* pa = (const float*)d_in[4];

    const int n = in_sizes[0] / HDIM;        // 100000
    const int E = in_sizes[1] / 2;           // 1600000
    const int NB = (n + (1 << BSH) - 1) >> BSH;   // 196 buckets

    float* out = (float*)d_out;

    // workspace layout (8B-aligned first):
    //   eb      : E int2          (12.8 MB)
    //   gbs     : n*128 ushort    (25.6 MB, slice-major 8 x n*16)
    //   dinv    : n floats
    //   row_ptr : n+1 ints
    //   col     : E ints
    //   bcnt    : 256 ints
    //   bbase   : 257 ints
    //   bcur    : 256 ints
    int2*           eb      = (int2*)d_ws;
    unsigned short* gbs     = (unsigned short*)(eb + (size_t)E);
    float*          dinv    = (float*)(gbs + (size_t)n * HDIM);
    int*            row_ptr = (int*)(dinv + n);
    int*            col     = row_ptr + (n + 1);
    int*            bcnt    = col + E;
    int*            bbase   = bcnt + 256;
    int*            bcur    = bbase + 257;

    hipMemsetAsync(bcnt, 0, 256 * sizeof(int), stream);

    const int nchunk = (E + CH - 1) / CH;
    binA_kernel<<<nchunk, 256, 0, stream>>>(ei + E, E, bcnt);
    scanB_kernel<<<1, 256, 0, stream>>>(bcnt, bbase, bcur, row_ptr, NB, n, E);
    binB_kernel<<<nchunk, 256, 0, stream>>>(ei, E, bcur, eb);
    binC_kernel<<<NB, 512, 0, stream>>>(eb, bbase, row_ptr, dinv, col, n);
    mfma_gemm_kernel<<<512, 256, 0, stream>>>(x, W, dinv, gbs, n);
    gather_kernel<<<NPB * 8, 256, 0, stream>>>(row_ptr, col, gbs, dinv, b, pa, out, n);
}

// Round 7
// 260.917 us; speedup vs baseline: 1.8676x; 1.8676x over previous
//
#include <hip/hip_runtime.h>
#include <math.h>

#define HDIM 128
#define BSH 9                 // bucket shift: 512 nodes per bucket
#define CH 4096               // edges per binning chunk

typedef __attribute__((ext_vector_type(8))) short short8;
typedef __attribute__((ext_vector_type(4))) float f32x4;

__device__ inline unsigned short bf16_hi(float f) {
    return (unsigned short)(__float_as_uint(f) >> 16);
}
__device__ inline unsigned short bf16_rn(float f) {
    unsigned int u = __float_as_uint(f);
    return (unsigned short)((u + 0x7FFF + ((u >> 16) & 1)) >> 16);
}

// ---------- 1. bucket histogram (196 buckets, LDS-aggregated) ----------
__global__ __launch_bounds__(256) void binA_kernel(
    const int* __restrict__ dst, int E, int* __restrict__ bcnt) {
    __shared__ int hist[256];
    const int t = threadIdx.x;
    const int c0 = blockIdx.x * CH;
    hist[t] = 0;
    __syncthreads();
    #pragma unroll
    for (int k = 0; k < CH / 256; ++k) {
        int e = c0 + t + (k << 8);
        if (e < E) atomicAdd(&hist[dst[e] >> BSH], 1);
    }
    __syncthreads();
    if (hist[t] > 0) atomicAdd(&bcnt[t], hist[t]);
}

// ---------- 2. scan bucket counts -> bbase / bcur; row_ptr[n]=E ----------
__global__ __launch_bounds__(256) void scanB_kernel(
    const int* __restrict__ bcnt, int* __restrict__ bbase, int* __restrict__ bcur,
    int* __restrict__ row_ptr, int NB, int n, int E) {
    __shared__ int s[256];
    const int t = threadIdx.x;
    int v = (t < NB) ? bcnt[t] : 0;
    s[t] = v;
    __syncthreads();
    for (int off = 1; off < 256; off <<= 1) {
        int u = (t >= off) ? s[t - off] : 0;
        __syncthreads();
        s[t] += u;
        __syncthreads();
    }
    int excl = s[t] - v;
    if (t < NB) { bbase[t] = excl; bcur[t] = excl; }
    if (t == 0) { bbase[NB] = E; row_ptr[n] = E; }
}

// ---------- 3. bin edges into bucket-major eb[] (packed: ldst<<23 | src) ----------
__global__ __launch_bounds__(256) void binB_kernel(
    const int* __restrict__ ei, int E,
    int* __restrict__ bcur, unsigned int* __restrict__ eb) {
    __shared__ int hist[256], base[256], cur[256];
    const int t = threadIdx.x;
    const int c0 = blockIdx.x * CH;
    hist[t] = 0;
    __syncthreads();

    int sv[CH / 256], dv[CH / 256];
    #pragma unroll
    for (int k = 0; k < CH / 256; ++k) {
        int e = c0 + t + (k << 8);
        if (e < E) {
            sv[k] = ei[e];
            dv[k] = ei[E + e];
            atomicAdd(&hist[dv[k] >> BSH], 1);
        } else {
            dv[k] = -1;
        }
    }
    __syncthreads();
    if (hist[t] > 0) base[t] = atomicAdd(&bcur[t], hist[t]);
    cur[t] = 0;
    __syncthreads();
    #pragma unroll
    for (int k = 0; k < CH / 256; ++k) {
        if (dv[k] >= 0) {
            int bkt = dv[k] >> BSH;
            int o = atomicAdd(&cur[bkt], 1);
            eb[(size_t)base[bkt] + o] =
                ((unsigned int)(dv[k] & ((1 << BSH) - 1)) << 23) | (unsigned int)sv[k];
        }
    }
}

// ---------- 4. per-bucket: LDS degree hist + scan -> row_ptr/dinv, CSR fill ----------
__global__ __launch_bounds__(512) void binC_kernel(
    const unsigned int* __restrict__ eb, const int* __restrict__ bbase,
    int* __restrict__ row_ptr, float* __restrict__ dinv,
    int* __restrict__ col, int n) {
    __shared__ int hist[512];
    __shared__ int cur[512];
    const int t = threadIdx.x;
    const int b = blockIdx.x;
    const int node0 = b << BSH;
    const int e0 = bbase[b];
    const int e1 = bbase[b + 1];

    hist[t] = 0;
    __syncthreads();
    for (int e = e0 + t; e < e1; e += 512)
        atomicAdd(&hist[eb[e] >> 23], 1);
    __syncthreads();
    int v = hist[t];
    for (int off = 1; off < 512; off <<= 1) {
        int u = (t >= off) ? hist[t - off] : 0;
        __syncthreads();
        hist[t] += u;
        __syncthreads();
    }
    int excl = hist[t] - v;
    int node = node0 + t;
    if (node < n) {
        row_ptr[node] = e0 + excl;
        dinv[node] = rsqrtf((float)v + 1.0f);
    }
    cur[t] = e0 + excl;
    __syncthreads();
    for (int e = e0 + t; e < e1; e += 512) {
        unsigned int p = eb[e];
        int pos = atomicAdd(&cur[p >> 23], 1);
        col[pos] = (int)(p & 0x7FFFFF);
    }
}

// ---------- 5. MFMA split-bf16 GEMM: gb[row][col] = bf16(dinv*(x@W^T)) ----------
// 3-term split: x*W ~= xh*Wh + xl*Wh + xh*Wl, fp32 accumulate, row-major bf16.
__global__ __launch_bounds__(256) void mfma_gemm_kernel(
    const float* __restrict__ x, const float* __restrict__ W,
    const float* __restrict__ dinv, unsigned short* __restrict__ gb, int n) {
    __shared__ uint4 Wh[2048];   // 32 KB
    __shared__ uint4 Wl[2048];   // 32 KB

    const int t = threadIdx.x;
    const int wave = t >> 6;
    const int lane = t & 63;
    const int q = lane >> 4;
    const int m = lane & 15;

    for (int idx = t; idx < 2048; idx += 256) {
        const int j = idx >> 4;
        const int c = idx & 15;
        const float4* wp = (const float4*)(W + (size_t)j * HDIM + c * 8);
        float4 va = wp[0], vb = wp[1];
        float vs[8] = {va.x, va.y, va.z, va.w, vb.x, vb.y, vb.z, vb.w};
        unsigned short h[8], l[8];
        #pragma unroll
        for (int k = 0; k < 8; ++k) {
            h[k] = bf16_hi(vs[k]);
            float hf = __uint_as_float((unsigned int)h[k] << 16);
            l[k] = bf16_hi(vs[k] - hf);
        }
        uint4 hch, lch;
        hch.x = (unsigned int)h[0] | ((unsigned int)h[1] << 16);
        hch.y = (unsigned int)h[2] | ((unsigned int)h[3] << 16);
        hch.z = (unsigned int)h[4] | ((unsigned int)h[5] << 16);
        hch.w = (unsigned int)h[6] | ((unsigned int)h[7] << 16);
        lch.x = (unsigned int)l[0] | ((unsigned int)l[1] << 16);
        lch.y = (unsigned int)l[2] | ((unsigned int)l[3] << 16);
        lch.z = (unsigned int)l[4] | ((unsigned int)l[5] << 16);
        lch.w = (unsigned int)l[6] | ((unsigned int)l[7] << 16);
        const int sidx = (j << 4) | (c ^ (j & 15));
        Wh[sidx] = hch;
        Wl[sidx] = lch;
    }
    __syncthreads();

    const int ngroups = (n + 127) >> 7;
    for (int grp = blockIdx.x; grp < ngroups; grp += gridDim.x) {
        const int rowbase = (grp << 7) + (wave << 5);

        f32x4 acc[2][8];
        #pragma unroll
        for (int mt = 0; mt < 2; ++mt)
            #pragma unroll
            for (int ct = 0; ct < 8; ++ct)
                acc[mt][ct] = (f32x4){0.f, 0.f, 0.f, 0.f};

        #pragma unroll
        for (int kk = 0; kk < 4; ++kk) {
            short8 ah[2], al[2];
            #pragma unroll
            for (int mt = 0; mt < 2; ++mt) {
                const int r = rowbase + (mt << 4) + m;
                float vs[8];
                if (r < n) {
                    const float4* xp = (const float4*)(x + (size_t)r * HDIM + (kk << 5) + (q << 3));
                    float4 va = xp[0], vb = xp[1];
                    vs[0] = va.x; vs[1] = va.y; vs[2] = va.z; vs[3] = va.w;
                    vs[4] = vb.x; vs[5] = vb.y; vs[6] = vb.z; vs[7] = vb.w;
                } else {
                    #pragma unroll
                    for (int k = 0; k < 8; ++k) vs[k] = 0.f;
                }
                #pragma unroll
                for (int k = 0; k < 8; ++k) {
                    unsigned short h = bf16_hi(vs[k]);
                    float hf = __uint_as_float((unsigned int)h << 16);
                    unsigned short lo = bf16_hi(vs[k] - hf);
                    ah[mt][k] = (short)h;
                    al[mt][k] = (short)lo;
                }
            }
            #pragma unroll
            for (int ct = 0; ct < 8; ++ct) {
                const int nn = (ct << 4) + m;
                const int sidx = (nn << 4) | (((kk << 2) + q) ^ m);
                short8 bh = *(const short8*)&Wh[sidx];
                short8 bl = *(const short8*)&Wl[sidx];
                #pragma unroll
                for (int mt = 0; mt < 2; ++mt) {
                    acc[mt][ct] = __builtin_amdgcn_mfma_f32_16x16x32_bf16(ah[mt], bh, acc[mt][ct], 0, 0, 0);
                    acc[mt][ct] = __builtin_amdgcn_mfma_f32_16x16x32_bf16(al[mt], bh, acc[mt][ct], 0, 0, 0);
                    acc[mt][ct] = __builtin_amdgcn_mfma_f32_16x16x32_bf16(ah[mt], bl, acc[mt][ct], 0, 0, 0);
                }
            }
        }

        #pragma unroll
        for (int mt = 0; mt < 2; ++mt) {
            #pragma unroll
            for (int rr = 0; rr < 4; ++rr) {
                const int grow = rowbase + (mt << 4) + (q << 2) + rr;
                if (grow < n) {
                    const float di = dinv[grow];
                    unsigned short* gp = gb + (size_t)grow * HDIM + m;
                    #pragma unroll
                    for (int ct = 0; ct < 8; ++ct)
                        gp[ct << 4] = bf16_rn(acc[mt][ct][rr] * di);
                }
            }
        }
    }
}

// ---------- 6. pull gather: quarter-wave per edge, 16B/lane ----------
// One wave per node. Quarter q handles edges beg+q, beg+q+4, ... Each lane
// loads uint4 (8 bf16 cols: l16*8..+7); full 256B row per quarter per edge.
// Cross-quarter shfl_xor reduction; out = dinv_i*(sum m_src + m_i) + b, PReLU.
__global__ __launch_bounds__(256) void gather_kernel(
    const int* __restrict__ row_ptr, const int* __restrict__ col,
    const uint4* __restrict__ gbr, const float* __restrict__ dinv,
    const float* __restrict__ bias, const float* __restrict__ prelu_a,
    float* __restrict__ out, int n) {
    const int wv = threadIdx.x >> 6;
    const int lane = threadIdx.x & 63;
    const int q = lane >> 4;
    const int l16 = lane & 15;
    const int i = blockIdx.x * 4 + wv;
    if (i >= n) return;

    const int beg = row_ptr[i];
    const int end = row_ptr[i + 1];

    float a[8];
    #pragma unroll
    for (int k = 0; k < 8; ++k) a[k] = 0.f;

    // self term, counted once (quarter 0)
    if (q == 0) {
        uint4 u = gbr[(size_t)i * 16 + l16];
        a[0] += __uint_as_float(u.x << 16);
        a[1] += __uint_as_float(u.x & 0xffff0000u);
        a[2] += __uint_as_float(u.y << 16);
        a[3] += __uint_as_float(u.y & 0xffff0000u);
        a[4] += __uint_as_float(u.z << 16);
        a[5] += __uint_as_float(u.z & 0xffff0000u);
        a[6] += __uint_as_float(u.w << 16);
        a[7] += __uint_as_float(u.w & 0xffff0000u);
    }

    int e = beg + q;
    for (; e + 4 < end; e += 8) {          // 2 edges per quarter per iter
        int s0 = col[e];
        int s1 = col[e + 4];
        uint4 u0 = gbr[(size_t)s0 * 16 + l16];
        uint4 u1 = gbr[(size_t)s1 * 16 + l16];
        a[0] += __uint_as_float(u0.x << 16);       a[0] += __uint_as_float(u1.x << 16);
        a[1] += __uint_as_float(u0.x & 0xffff0000u); a[1] += __uint_as_float(u1.x & 0xffff0000u);
        a[2] += __uint_as_float(u0.y << 16);       a[2] += __uint_as_float(u1.y << 16);
        a[3] += __uint_as_float(u0.y & 0xffff0000u); a[3] += __uint_as_float(u1.y & 0xffff0000u);
        a[4] += __uint_as_float(u0.z << 16);       a[4] += __uint_as_float(u1.z << 16);
        a[5] += __uint_as_float(u0.z & 0xffff0000u); a[5] += __uint_as_float(u1.z & 0xffff0000u);
        a[6] += __uint_as_float(u0.w << 16);       a[6] += __uint_as_float(u1.w << 16);
        a[7] += __uint_as_float(u0.w & 0xffff0000u); a[7] += __uint_as_float(u1.w & 0xffff0000u);
    }
    if (e < end) {
        int s = col[e];
        uint4 u = gbr[(size_t)s * 16 + l16];
        a[0] += __uint_as_float(u.x << 16);
        a[1] += __uint_as_float(u.x & 0xffff0000u);
        a[2] += __uint_as_float(u.y << 16);
        a[3] += __uint_as_float(u.y & 0xffff0000u);
        a[4] += __uint_as_float(u.z << 16);
        a[5] += __uint_as_float(u.z & 0xffff0000u);
        a[6] += __uint_as_float(u.w << 16);
        a[7] += __uint_as_float(u.w & 0xffff0000u);
    }

    // reduce across quarters (all lanes end with full sums)
    #pragma unroll
    for (int k = 0; k < 8; ++k) {
        a[k] += __shfl_xor(a[k], 16);
        a[k] += __shfl_xor(a[k], 32);
    }

    // epilogue: lane writes 2 cols (c0 = l16*8 + q*2)
    const float di = dinv[i];
    const float aa = prelu_a[0];
    const int c0 = (l16 << 3) + (q << 1);
    float2 bb = *(const float2*)(bias + c0);
    float v0 = di * a[(q << 1) + 0] + bb.x;
    float v1 = di * a[(q << 1) + 1] + bb.y;
    v0 = v0 >= 0.f ? v0 : aa * v0;
    v1 = v1 >= 0.f ? v1 : aa * v1;
    *(float2*)(out + (size_t)i * HDIM + c0) = make_float2(v0, v1);
}

extern "C" void kernel_launch(void* const* d_in, const int* in_sizes, int n_in,
                              void* d_out, int out_size, void* d_ws, size_t ws_size,
                              hipStream_t stream) {
    const float* x  = (const float*)d_in[0];
    const int*   ei = (const int*)d_in[1];   // edge_index (2, E), int32
    const float* W  = (const float*)d_in[2];
    const float* b  = (const float*)d_in[3];
    const float* pa = (const float*)d_in[4];

    const int n = in_sizes[0] / HDIM;        // 100000
    const int E = in_sizes[1] / 2;           // 1600000
    const int NB = (n + (1 << BSH) - 1) >> BSH;   // 196 buckets

    float* out = (float*)d_out;

    // workspace layout (16B-aligned first):
    //   gb      : n*128 ushort    (25.6 MB, row-major)
    //   eb      : E uint          (6.4 MB, packed ldst|src)
    //   dinv    : n floats
    //   row_ptr : n+1 ints
    //   col     : E ints
    //   bcnt/bbase/bcur
    unsigned short* gb      = (unsigned short*)d_ws;
    unsigned int*   eb      = (unsigned int*)(gb + (size_t)n * HDIM);
    float*          dinv    = (float*)(eb + (size_t)E);
    int*            row_ptr = (int*)(dinv + n);
    int*            col     = row_ptr + (n + 1);
    int*            bcnt    = col + E;
    int*            bbase   = bcnt + 256;
    int*            bcur    = bbase + 257;

    hipMemsetAsync(bcnt, 0, 256 * sizeof(int), stream);

    const int nchunk = (E + CH - 1) / CH;
    binA_kernel<<<nchunk, 256, 0, stream>>>(ei + E, E, bcnt);
    scanB_kernel<<<1, 256, 0, stream>>>(bcnt, bbase, bcur, row_ptr, NB, n, E);
    binB_kernel<<<nchunk, 256, 0, stream>>>(ei, E, bcur, eb);
    binC_kernel<<<NB, 512, 0, stream>>>(eb, bbase, row_ptr, dinv, col, n);
    mfma_gemm_kernel<<<512, 256, 0, stream>>>(x, W, dinv, gb, n);
    gather_kernel<<<(n + 3) / 4, 256, 0, stream>>>(row_ptr, col, (const uint4*)gb, dinv, b, pa, out, n);
}